// Round 1
// baseline (44.954 us; speedup 1.0000x reference)
//
#include <hip/hip_runtime.h>
#include <hip/hip_bf16.h>

typedef short s16x8 __attribute__((ext_vector_type(8)));
typedef float f32x4 __attribute__((ext_vector_type(4)));

#define M_DIM   128
#define K_DIM   131072          // C*W*H = 512*16*16
#define NSPLIT  256             // split-K blocks
#define KC      (K_DIM / NSPLIT) // 512 per block
#define BK      64              // K per LDS step
#define NSTEP   (KC / BK)       // 8
#define THREADS 512

__device__ __forceinline__ short f2bf(float f) {
    unsigned u = __builtin_bit_cast(unsigned, f);
    u += 0x7fffu + ((u >> 16) & 1u);   // round-to-nearest-even
    return (short)(u >> 16);
}

__device__ __forceinline__ s16x8 cvt8(float4 a, float4 b) {
    s16x8 r;
    r[0] = f2bf(a.x); r[1] = f2bf(a.y); r[2] = f2bf(a.z); r[3] = f2bf(a.w);
    r[4] = f2bf(b.x); r[5] = f2bf(b.y); r[6] = f2bf(b.z); r[7] = f2bf(b.w);
    return r;
}

// Split-K GEMM: block b computes partial[i][j] = sum_{k in chunk b} x[i,k]*y[j,k]
__global__ __launch_bounds__(THREADS) void gemm_splitk(
    const float* __restrict__ x, const float* __restrict__ y,
    const float* __restrict__ kern,
    float* __restrict__ ws, float* __restrict__ out, int use_ws)
{
    // [buf][mat][row][k]  bf16, 64 KiB total
    __shared__ __align__(16) short lds[2][2][M_DIM][BK];

    const int t    = threadIdx.x;
    const long kb0 = (long)blockIdx.x * KC;

    // ---- staging mapping: thread t loads rows (t>>3) and (t>>3)+64, 8-float group t&7
    const int srow = t >> 3;          // 0..63
    const int sg   = t & 7;           // 0..7
    const int wofs = (sg ^ (srow & 7)) * 8;   // swizzled short-offset ((srow+64)&7 == srow&7)

    const float* xa = x + (size_t)srow        * K_DIM + kb0 + sg * 8;
    const float* xb = x + (size_t)(srow + 64) * K_DIM + kb0 + sg * 8;
    const float* ya = y + (size_t)srow        * K_DIM + kb0 + sg * 8;
    const float* yb = y + (size_t)(srow + 64) * K_DIM + kb0 + sg * 8;

    // ---- wave tile: 8 waves in 2(row)x4(col); each wave 64x32 = 4x2 frags of 16x16
    const int wave = t >> 6;
    const int lane = t & 63;
    const int wr   = wave >> 2;       // 0..1
    const int wc   = wave & 3;        // 0..3
    const int l15  = lane & 15;
    const int l4   = lane >> 4;

    f32x4 acc[4][2] = {};

    float4 r0, r1, r2, r3, r4, r5, r6, r7;

    auto stage_load = [&](long kb) {
        r0 = *(const float4*)(xa + kb); r1 = *(const float4*)(xa + kb + 4);
        r2 = *(const float4*)(xb + kb); r3 = *(const float4*)(xb + kb + 4);
        r4 = *(const float4*)(ya + kb); r5 = *(const float4*)(ya + kb + 4);
        r6 = *(const float4*)(yb + kb); r7 = *(const float4*)(yb + kb + 4);
    };
    auto stage_write = [&](int buf) {
        *(s16x8*)&lds[buf][0][srow     ][wofs] = cvt8(r0, r1);
        *(s16x8*)&lds[buf][0][srow + 64][wofs] = cvt8(r2, r3);
        *(s16x8*)&lds[buf][1][srow     ][wofs] = cvt8(r4, r5);
        *(s16x8*)&lds[buf][1][srow + 64][wofs] = cvt8(r6, r7);
    };
    auto compute = [&](int buf) {
        #pragma unroll
        for (int ks = 0; ks < 2; ++ks) {
            s16x8 af[4], bf[2];
            const int g = ks * 4 + l4;          // 8-elem k-group 0..7
            #pragma unroll
            for (int m = 0; m < 4; ++m) {
                const int row = wr * 64 + m * 16 + l15;
                af[m] = *(const s16x8*)&lds[buf][0][row][(g ^ (row & 7)) * 8];
            }
            #pragma unroll
            for (int n = 0; n < 2; ++n) {
                const int row = wc * 32 + n * 16 + l15;
                bf[n] = *(const s16x8*)&lds[buf][1][row][(g ^ (row & 7)) * 8];
            }
            #pragma unroll
            for (int m = 0; m < 4; ++m)
                #pragma unroll
                for (int n = 0; n < 2; ++n)
                    acc[m][n] = __builtin_amdgcn_mfma_f32_16x16x32_bf16(
                        af[m], bf[n], acc[m][n], 0, 0, 0);
        }
    };

    stage_load(0);
    stage_write(0);
    __syncthreads();

    for (int s = 0; s < NSTEP; ++s) {
        const int buf = s & 1;
        if (s + 1 < NSTEP) {
            stage_load((long)(s + 1) * BK);   // HBM latency hides under MFMA
            compute(buf);
            stage_write(buf ^ 1);             // waits on loads via reg deps
            __syncthreads();
        } else {
            compute(buf);
        }
    }

    // ---- epilogue: D frag mapping col=lane&15, row=(lane>>4)*4+reg
    if (use_ws) {
        float* wp = ws + (size_t)blockIdx.x * (M_DIM * M_DIM);
        #pragma unroll
        for (int m = 0; m < 4; ++m) {
            const int row = wr * 64 + m * 16 + l4 * 4;
            #pragma unroll
            for (int n = 0; n < 2; ++n) {
                const int col = wc * 32 + n * 16 + l15;
                #pragma unroll
                for (int r = 0; r < 4; ++r)
                    wp[(size_t)(row + r) * M_DIM + col] = acc[m][n][r];
            }
        }
    } else {
        const float scale = kern[0] * (1.0f / 512.0f);  // kernel[0]/C
        #pragma unroll
        for (int m = 0; m < 4; ++m) {
            const int row = wr * 64 + m * 16 + l4 * 4;
            #pragma unroll
            for (int n = 0; n < 2; ++n) {
                const int col = wc * 32 + n * 16 + l15;
                #pragma unroll
                for (int r = 0; r < 4; ++r)
                    atomicAdd(out + (size_t)(row + r) * M_DIM + col,
                              acc[m][n][r] * scale);
            }
        }
    }
}

// out[e] = scale * sum_s ws[s][e] + 0.1
__global__ __launch_bounds__(256) void reduce_k(
    const float* __restrict__ ws, const float* __restrict__ kern,
    float* __restrict__ out)
{
    const int e = blockIdx.x * 256 + threadIdx.x;   // grid 64 -> 16384
    float s0 = 0.f, s1 = 0.f, s2 = 0.f, s3 = 0.f;
    #pragma unroll 8
    for (int s = 0; s < NSPLIT; s += 4) {
        s0 += ws[(size_t)(s    ) * 16384 + e];
        s1 += ws[(size_t)(s + 1) * 16384 + e];
        s2 += ws[(size_t)(s + 2) * 16384 + e];
        s3 += ws[(size_t)(s + 3) * 16384 + e];
    }
    const float scale = kern[0] * (1.0f / 512.0f);
    out[e] = ((s0 + s1) + (s2 + s3)) * scale + 0.1f;
}

__global__ __launch_bounds__(256) void init_k(float* __restrict__ out) {
    out[blockIdx.x * 256 + threadIdx.x] = 0.1f;
}

extern "C" void kernel_launch(void* const* d_in, const int* in_sizes, int n_in,
                              void* d_out, int out_size, void* d_ws, size_t ws_size,
                              hipStream_t stream) {
    const float* x    = (const float*)d_in[0];
    const float* y    = (const float*)d_in[1];
    const float* kern = (const float*)d_in[2];
    float* out = (float*)d_out;

    const size_t need = (size_t)NSPLIT * M_DIM * M_DIM * sizeof(float);
    if (ws_size >= need && d_ws != nullptr) {
        float* ws = (float*)d_ws;
        gemm_splitk<<<NSPLIT, THREADS, 0, stream>>>(x, y, kern, ws, out, 1);
        reduce_k<<<M_DIM * M_DIM / 256, 256, 0, stream>>>(ws, kern, out);
    } else {
        init_k<<<M_DIM * M_DIM / 256, 256, 0, stream>>>(out);
        gemm_splitk<<<NSPLIT, THREADS, 0, stream>>>(x, y, kern, nullptr, out, 0);
    }
}

// Round 2
// 32.634 us; speedup vs baseline: 1.3775x; 1.3775x over previous
//
#include <hip/hip_runtime.h>
#include <hip/hip_bf16.h>

typedef short s16x8 __attribute__((ext_vector_type(8)));
typedef float f32x4 __attribute__((ext_vector_type(4)));

#define M_DIM   128
#define K_DIM   131072           // C*W*H = 512*16*16
#define NSPLIT  512              // split-K blocks -> 2 blocks/CU
#define KC      (K_DIM / NSPLIT) // 256 per block
#define BK      64               // K per LDS step
#define NSTEP   (KC / BK)        // 4
#define THREADS 512
#define OUT_N   (M_DIM * M_DIM)  // 16384

__device__ __forceinline__ short f2bf(float f) {
    unsigned u = __builtin_bit_cast(unsigned, f);
    u += 0x7fffu + ((u >> 16) & 1u);   // round-to-nearest-even
    return (short)(u >> 16);
}
__device__ __forceinline__ float bf2f(unsigned short h) {
    unsigned u = ((unsigned)h) << 16;
    return __builtin_bit_cast(float, u);
}

__device__ __forceinline__ s16x8 cvt8(float4 a, float4 b) {
    s16x8 r;
    r[0] = f2bf(a.x); r[1] = f2bf(a.y); r[2] = f2bf(a.z); r[3] = f2bf(a.w);
    r[4] = f2bf(b.x); r[5] = f2bf(b.y); r[6] = f2bf(b.z); r[7] = f2bf(b.w);
    return r;
}

// Split-K GEMM: block b computes partial[i][j] = sum_{k in chunk b} x[i,k]*y[j,k]
__global__ __launch_bounds__(THREADS) void gemm_splitk(
    const float* __restrict__ x, const float* __restrict__ y,
    const float* __restrict__ kern,
    unsigned short* __restrict__ ws, float* __restrict__ out, int use_ws)
{
    // [buf][mat][row][k]  bf16, 64 KiB total -> 2 blocks/CU
    __shared__ __align__(16) short lds[2][2][M_DIM][BK];

    const int t    = threadIdx.x;
    const long kb0 = (long)blockIdx.x * KC;

    // staging: thread t loads rows (t>>3), (t>>3)+64; 8-float group t&7
    const int srow = t >> 3;          // 0..63
    const int sg   = t & 7;           // 0..7
    const int wofs = (sg ^ (srow & 7)) * 8;   // swizzled ((srow+64)&7 == srow&7)

    const float* xa = x + (size_t)srow        * K_DIM + kb0 + sg * 8;
    const float* xb = x + (size_t)(srow + 64) * K_DIM + kb0 + sg * 8;
    const float* ya = y + (size_t)srow        * K_DIM + kb0 + sg * 8;
    const float* yb = y + (size_t)(srow + 64) * K_DIM + kb0 + sg * 8;

    // wave tile: 8 waves 2(row)x4(col); each wave 64x32 = 4x2 frags of 16x16
    const int wave = t >> 6;
    const int lane = t & 63;
    const int wr   = wave >> 2;
    const int wc   = wave & 3;
    const int l15  = lane & 15;
    const int l4   = lane >> 4;

    f32x4 acc[4][2] = {};
    float4 r0, r1, r2, r3, r4, r5, r6, r7;

    auto stage_load = [&](long kb) {
        r0 = *(const float4*)(xa + kb); r1 = *(const float4*)(xa + kb + 4);
        r2 = *(const float4*)(xb + kb); r3 = *(const float4*)(xb + kb + 4);
        r4 = *(const float4*)(ya + kb); r5 = *(const float4*)(ya + kb + 4);
        r6 = *(const float4*)(yb + kb); r7 = *(const float4*)(yb + kb + 4);
    };
    auto stage_write = [&](int buf) {
        *(s16x8*)&lds[buf][0][srow     ][wofs] = cvt8(r0, r1);
        *(s16x8*)&lds[buf][0][srow + 64][wofs] = cvt8(r2, r3);
        *(s16x8*)&lds[buf][1][srow     ][wofs] = cvt8(r4, r5);
        *(s16x8*)&lds[buf][1][srow + 64][wofs] = cvt8(r6, r7);
    };
    auto compute = [&](int buf) {
        #pragma unroll
        for (int ks = 0; ks < 2; ++ks) {
            s16x8 af[4], bf[2];
            const int g = ks * 4 + l4;
            #pragma unroll
            for (int m = 0; m < 4; ++m) {
                const int row = wr * 64 + m * 16 + l15;
                af[m] = *(const s16x8*)&lds[buf][0][row][(g ^ (row & 7)) * 8];
            }
            #pragma unroll
            for (int n = 0; n < 2; ++n) {
                const int row = wc * 32 + n * 16 + l15;
                bf[n] = *(const s16x8*)&lds[buf][1][row][(g ^ (row & 7)) * 8];
            }
            #pragma unroll
            for (int m = 0; m < 4; ++m)
                #pragma unroll
                for (int n = 0; n < 2; ++n)
                    acc[m][n] = __builtin_amdgcn_mfma_f32_16x16x32_bf16(
                        af[m], bf[n], acc[m][n], 0, 0, 0);
        }
    };

    stage_load(0);
    stage_write(0);
    __syncthreads();

    for (int s = 0; s < NSTEP; ++s) {
        const int buf = s & 1;
        if (s + 1 < NSTEP) {
            stage_load((long)(s + 1) * BK);   // HBM latency hides under MFMA
            compute(buf);
            stage_write(buf ^ 1);
            __syncthreads();
        } else {
            compute(buf);
        }
    }

    // epilogue: D frag mapping col=lane&15, row=(lane>>4)*4+reg
    if (use_ws) {
        unsigned short* wp = ws + (size_t)blockIdx.x * OUT_N;
        #pragma unroll
        for (int m = 0; m < 4; ++m) {
            const int row = wr * 64 + m * 16 + l4 * 4;
            #pragma unroll
            for (int n = 0; n < 2; ++n) {
                const int col = wc * 32 + n * 16 + l15;
                #pragma unroll
                for (int r = 0; r < 4; ++r)
                    wp[(size_t)(row + r) * M_DIM + col] =
                        (unsigned short)f2bf(acc[m][n][r]);
            }
        }
    } else {
        const float scale = kern[0] * (1.0f / 512.0f);
        #pragma unroll
        for (int m = 0; m < 4; ++m) {
            const int row = wr * 64 + m * 16 + l4 * 4;
            #pragma unroll
            for (int n = 0; n < 2; ++n) {
                const int col = wc * 32 + n * 16 + l15;
                #pragma unroll
                for (int r = 0; r < 4; ++r)
                    atomicAdd(out + (size_t)(row + r) * M_DIM + col,
                              acc[m][n][r] * scale);
            }
        }
    }
}

// 256 blocks x 256 threads: block b reduces 64 outputs over all 512 splits.
__global__ __launch_bounds__(256) void reduce_k(
    const unsigned short* __restrict__ ws, const float* __restrict__ kern,
    float* __restrict__ out)
{
    __shared__ float red[16][16][4];   // [s-chunk][quad][elem]
    const int b  = blockIdx.x;         // 256
    const int qi = threadIdx.x & 15;   // 16 quads of 4 outputs = 64 outputs
    const int sc = threadIdx.x >> 4;   // 16 s-chunks of 32 splits
    const int e0 = b * 64 + qi * 4;

    float a0 = 0.f, a1 = 0.f, a2 = 0.f, a3 = 0.f;
    #pragma unroll 4
    for (int s = sc * 32; s < sc * 32 + 32; ++s) {
        ushort4 v = *(const ushort4*)(ws + (size_t)s * OUT_N + e0);
        a0 += bf2f(v.x); a1 += bf2f(v.y); a2 += bf2f(v.z); a3 += bf2f(v.w);
    }
    red[sc][qi][0] = a0; red[sc][qi][1] = a1;
    red[sc][qi][2] = a2; red[sc][qi][3] = a3;
    __syncthreads();
    for (int off = 8; off > 0; off >>= 1) {
        if (sc < off) {
            #pragma unroll
            for (int r = 0; r < 4; ++r)
                red[sc][qi][r] += red[sc + off][qi][r];
        }
        __syncthreads();
    }
    if (sc == 0) {
        const float scale = kern[0] * (1.0f / 512.0f);
        float4 o;
        o.x = red[0][qi][0] * scale + 0.1f;
        o.y = red[0][qi][1] * scale + 0.1f;
        o.z = red[0][qi][2] * scale + 0.1f;
        o.w = red[0][qi][3] * scale + 0.1f;
        *(float4*)(out + e0) = o;
    }
}

__global__ __launch_bounds__(256) void init_k(float* __restrict__ out) {
    out[blockIdx.x * 256 + threadIdx.x] = 0.1f;
}

extern "C" void kernel_launch(void* const* d_in, const int* in_sizes, int n_in,
                              void* d_out, int out_size, void* d_ws, size_t ws_size,
                              hipStream_t stream) {
    const float* x    = (const float*)d_in[0];
    const float* y    = (const float*)d_in[1];
    const float* kern = (const float*)d_in[2];
    float* out = (float*)d_out;

    const size_t need = (size_t)NSPLIT * OUT_N * sizeof(unsigned short);
    if (ws_size >= need && d_ws != nullptr) {
        unsigned short* ws = (unsigned short*)d_ws;
        gemm_splitk<<<NSPLIT, THREADS, 0, stream>>>(x, y, kern, ws, out, 1);
        reduce_k<<<256, 256, 0, stream>>>(ws, kern, out);
    } else {
        init_k<<<OUT_N / 256, 256, 0, stream>>>(out);
        gemm_splitk<<<NSPLIT, THREADS, 0, stream>>>(x, y, kern, nullptr, out, 0);
    }
}

// Round 3
// 29.769 us; speedup vs baseline: 1.5101x; 1.0962x over previous
//
#include <hip/hip_runtime.h>
#include <hip/hip_bf16.h>

typedef short s16x8 __attribute__((ext_vector_type(8)));
typedef float f32x4 __attribute__((ext_vector_type(4)));

#define M_DIM   128
#define K_DIM   131072           // C*W*H = 512*16*16
#define NSPLIT  256              // split-K blocks -> 1 block/CU
#define KC      (K_DIM / NSPLIT) // 512 per block
#define BK      64               // K per LDS step
#define NSTEP   (KC / BK)        // 8
#define THREADS 512
#define OUT_N   (M_DIM * M_DIM)  // 16384

__device__ __forceinline__ short f2bf(float f) {
    unsigned u = __builtin_bit_cast(unsigned, f);
    u += 0x7fffu + ((u >> 16) & 1u);   // round-to-nearest-even
    return (short)(u >> 16);
}
__device__ __forceinline__ float bf2f(unsigned short h) {
    unsigned u = ((unsigned)h) << 16;
    return __builtin_bit_cast(float, u);
}
__device__ __forceinline__ s16x8 cvt8(float4 a, float4 b) {
    s16x8 r;
    r[0] = f2bf(a.x); r[1] = f2bf(a.y); r[2] = f2bf(a.z); r[3] = f2bf(a.w);
    r[4] = f2bf(b.x); r[5] = f2bf(b.y); r[6] = f2bf(b.z); r[7] = f2bf(b.w);
    return r;
}

// Split-K GEMM: block b computes partial[i][j] = sum_{k in chunk b} x[i,k]*y[j,k]
// Depth-2 load pipeline: loads for step s+2 issue while step s computes and
// step s+1 (loaded last iteration, already landed) is written to LDS.
__global__ __launch_bounds__(THREADS) void gemm_splitk(
    const float* __restrict__ x, const float* __restrict__ y,
    const float* __restrict__ kern,
    unsigned short* __restrict__ ws, float* __restrict__ out, int use_ws)
{
    // [buf][mat][row][k]  bf16, 64 KiB
    __shared__ __align__(16) short lds[2][2][M_DIM][BK];

    const int t    = threadIdx.x;
    const long kb0 = (long)blockIdx.x * KC;

    // staging: thread t handles rows (t>>3), (t>>3)+64; 8-float group t&7
    const int srow = t >> 3;          // 0..63
    const int sg   = t & 7;           // 0..7
    const int wofs = (sg ^ (srow & 7)) * 8;   // swizzled ((srow+64)&7 == srow&7)

    const float* xa = x + (size_t)srow        * K_DIM + kb0 + sg * 8;
    const float* xb = x + (size_t)(srow + 64) * K_DIM + kb0 + sg * 8;
    const float* ya = y + (size_t)srow        * K_DIM + kb0 + sg * 8;
    const float* yb = y + (size_t)(srow + 64) * K_DIM + kb0 + sg * 8;

    // wave tile: 8 waves 2(row)x4(col); each wave 64x32 = 4x2 frags of 16x16
    const int wave = t >> 6;
    const int lane = t & 63;
    const int wr   = wave >> 2;
    const int wc   = wave & 3;
    const int l15  = lane & 15;
    const int l4   = lane >> 4;

    f32x4 acc[4][2] = {};

    // two independent staging register sets (static names -> no scratch)
    float4 A0,A1,A2,A3,A4,A5,A6,A7;
    float4 B0,B1,B2,B3,B4,B5,B6,B7;

    #define STAGE_LOAD(R, kb)                                            \
        R##0 = *(const float4*)(xa + (kb)); R##1 = *(const float4*)(xa + (kb) + 4); \
        R##2 = *(const float4*)(xb + (kb)); R##3 = *(const float4*)(xb + (kb) + 4); \
        R##4 = *(const float4*)(ya + (kb)); R##5 = *(const float4*)(ya + (kb) + 4); \
        R##6 = *(const float4*)(yb + (kb)); R##7 = *(const float4*)(yb + (kb) + 4);

    #define STAGE_WRITE(R, buf)                                          \
        *(s16x8*)&lds[buf][0][srow     ][wofs] = cvt8(R##0, R##1);       \
        *(s16x8*)&lds[buf][0][srow + 64][wofs] = cvt8(R##2, R##3);       \
        *(s16x8*)&lds[buf][1][srow     ][wofs] = cvt8(R##4, R##5);       \
        *(s16x8*)&lds[buf][1][srow + 64][wofs] = cvt8(R##6, R##7);

    auto compute = [&](int buf) {
        #pragma unroll
        for (int ks = 0; ks < 2; ++ks) {
            s16x8 af[4], bf[2];
            const int g = ks * 4 + l4;
            #pragma unroll
            for (int m = 0; m < 4; ++m) {
                const int row = wr * 64 + m * 16 + l15;
                af[m] = *(const s16x8*)&lds[buf][0][row][(g ^ (row & 7)) * 8];
            }
            #pragma unroll
            for (int n = 0; n < 2; ++n) {
                const int row = wc * 32 + n * 16 + l15;
                bf[n] = *(const s16x8*)&lds[buf][1][row][(g ^ (row & 7)) * 8];
            }
            #pragma unroll
            for (int m = 0; m < 4; ++m)
                #pragma unroll
                for (int n = 0; n < 2; ++n)
                    acc[m][n] = __builtin_amdgcn_mfma_f32_16x16x32_bf16(
                        af[m], bf[n], acc[m][n], 0, 0, 0);
        }
    };

    // prologue: steps 0,1 in flight; write step 0
    STAGE_LOAD(A, 0)
    STAGE_LOAD(B, BK)
    STAGE_WRITE(A, 0)
    __syncthreads();

    #pragma unroll
    for (int s = 0; s < NSTEP; s += 2) {
        // iter s (even): compute buf0; write step s+1 (set B) -> buf1
        if (s + 2 < NSTEP) { STAGE_LOAD(A, (long)(s + 2) * BK) }
        compute(0);
        STAGE_WRITE(B, 1)
        __syncthreads();
        // iter s+1 (odd): compute buf1; write step s+2 (set A) -> buf0
        if (s + 3 < NSTEP) { STAGE_LOAD(B, (long)(s + 3) * BK) }
        compute(1);
        if (s + 2 < NSTEP) { STAGE_WRITE(A, 0) }
        __syncthreads();
    }

    // epilogue: D frag mapping col=lane&15, row=(lane>>4)*4+reg
    if (use_ws) {
        unsigned short* wp = ws + (size_t)blockIdx.x * OUT_N;
        #pragma unroll
        for (int m = 0; m < 4; ++m) {
            const int row = wr * 64 + m * 16 + l4 * 4;
            #pragma unroll
            for (int n = 0; n < 2; ++n) {
                const int col = wc * 32 + n * 16 + l15;
                #pragma unroll
                for (int r = 0; r < 4; ++r)
                    wp[(size_t)(row + r) * M_DIM + col] =
                        (unsigned short)f2bf(acc[m][n][r]);
            }
        }
    } else {
        const float scale = kern[0] * (1.0f / 512.0f);
        #pragma unroll
        for (int m = 0; m < 4; ++m) {
            const int row = wr * 64 + m * 16 + l4 * 4;
            #pragma unroll
            for (int n = 0; n < 2; ++n) {
                const int col = wc * 32 + n * 16 + l15;
                #pragma unroll
                for (int r = 0; r < 4; ++r)
                    atomicAdd(out + (size_t)(row + r) * M_DIM + col,
                              acc[m][n][r] * scale);
            }
        }
    }
    #undef STAGE_LOAD
    #undef STAGE_WRITE
}

// 256 blocks x 256 threads: block b reduces 64 outputs over all 256 splits.
__global__ __launch_bounds__(256) void reduce_k(
    const unsigned short* __restrict__ ws, const float* __restrict__ kern,
    float* __restrict__ out)
{
    __shared__ float red[16][16][4];   // [s-chunk][quad][elem]
    const int b  = blockIdx.x;         // 256
    const int qi = threadIdx.x & 15;   // 16 quads of 4 outputs = 64 outputs
    const int sc = threadIdx.x >> 4;   // 16 s-chunks of 16 splits
    const int e0 = b * 64 + qi * 4;

    float a0 = 0.f, a1 = 0.f, a2 = 0.f, a3 = 0.f;
    #pragma unroll 4
    for (int s = sc * 16; s < sc * 16 + 16; ++s) {
        ushort4 v = *(const ushort4*)(ws + (size_t)s * OUT_N + e0);
        a0 += bf2f(v.x); a1 += bf2f(v.y); a2 += bf2f(v.z); a3 += bf2f(v.w);
    }
    red[sc][qi][0] = a0; red[sc][qi][1] = a1;
    red[sc][qi][2] = a2; red[sc][qi][3] = a3;
    __syncthreads();
    for (int off = 8; off > 0; off >>= 1) {
        if (sc < off) {
            #pragma unroll
            for (int r = 0; r < 4; ++r)
                red[sc][qi][r] += red[sc + off][qi][r];
        }
        __syncthreads();
    }
    if (sc == 0) {
        const float scale = kern[0] * (1.0f / 512.0f);
        float4 o;
        o.x = red[0][qi][0] * scale + 0.1f;
        o.y = red[0][qi][1] * scale + 0.1f;
        o.z = red[0][qi][2] * scale + 0.1f;
        o.w = red[0][qi][3] * scale + 0.1f;
        *(float4*)(out + e0) = o;
    }
}

__global__ __launch_bounds__(256) void init_k(float* __restrict__ out) {
    out[blockIdx.x * 256 + threadIdx.x] = 0.1f;
}

extern "C" void kernel_launch(void* const* d_in, const int* in_sizes, int n_in,
                              void* d_out, int out_size, void* d_ws, size_t ws_size,
                              hipStream_t stream) {
    const float* x    = (const float*)d_in[0];
    const float* y    = (const float*)d_in[1];
    const float* kern = (const float*)d_in[2];
    float* out = (float*)d_out;

    const size_t need = (size_t)NSPLIT * OUT_N * sizeof(unsigned short);
    if (ws_size >= need && d_ws != nullptr) {
        unsigned short* ws = (unsigned short*)d_ws;
        gemm_splitk<<<NSPLIT, THREADS, 0, stream>>>(x, y, kern, ws, out, 1);
        reduce_k<<<256, 256, 0, stream>>>(ws, kern, out);
    } else {
        init_k<<<OUT_N / 256, 256, 0, stream>>>(out);
        gemm_splitk<<<NSPLIT, THREADS, 0, stream>>>(x, y, kern, nullptr, out, 0);
    }
}